// Round 3
// baseline (347.540 us; speedup 1.0000x reference)
//
#include <hip/hip_runtime.h>
#include <math.h>

#define NB    128
#define NG    52
#define NGG   2704          // NG*NG
#define NA    3
#define NCLS  15
#define NCH   20
#define NQ    8112          // NA*NGG
#define TOTAL 1038336       // NB*NQ
#define BLK   256
#define NBLK  (TOTAL/BLK)   // 4056 (exact)
#define FPB   (BLK*NCH)     // 5120 floats = 20.5 KB LDS -> 7 blocks/CU
#define NQUAD ((FPB-4)/4)   // 1279 aligned float4 stores per block

typedef float f4 __attribute__((ext_vector_type(4)));

// ws layout: [0..7] u64 fixed-point loss accumulator, [8..11] u32 done-counter
#define FIXSCALE 4294967296.0   // 2^32 (double)

// ---- single fused kernel: transform + all loss terms + deterministic reduce
__global__ __launch_bounds__(BLK) void main_kernel(const float* __restrict__ x,
                                                   const float* __restrict__ labels,
                                                   float* __restrict__ out,
                                                   unsigned long long* __restrict__ ws) {
    __shared__ __align__(16) float sm[FPB];   // block's 5120 out floats, shifted by -3
    __shared__ float wred[BLK/64];

    int t = threadIdx.x;
    int cell = blockIdx.x * BLK + t;          // one cell per thread
    int b  = cell / NQ;
    int r  = cell - b * NQ;
    int a  = r / NGG;
    int ji = r - a * NGG;

    const float* __restrict__ xp = x + ((size_t)(b*60 + a*20)) * NGG + ji;
    float z[NCH];
    #pragma unroll
    for (int c = 0; c < NCH; c++) z[c] = xp[c * NGG];

    float v[NCH];
    float conf = 1.0f / (1.0f + __expf(-z[4]));
    v[0] = 8.0f / (1.0f + __expf(-z[0]));
    v[1] = 8.0f / (1.0f + __expf(-z[1]));
    v[2] = 8.0f * z[2];
    v[3] = 8.0f * z[3];
    v[4] = conf;
    float m = z[5];
    #pragma unroll
    for (int c = 6; c < NCH; c++) m = fmaxf(m, z[c]);
    float s = 0.0f;
    #pragma unroll
    for (int c = 0; c < NCLS; c++) { v[5+c] = __expf(z[5+c] - m); s += v[5+c]; }
    float inv = 1.0f / s;
    #pragma unroll
    for (int c = 0; c < NCLS; c++) v[5+c] *= inv;

    // ---- per-batch target logic ----
    float gx = labels[b*5+0] * (float)NG;
    float gy = labels[b*5+1] * (float)NG;
    float gw = labels[b*5+2] * (float)NG;
    float gh = labels[b*5+3] * (float)NG;
    int  gcls = (int)labels[b*5+4];
    int gi = (int)gx, gj = (int)gy;
    float gwgh = gw * gh;
    float i0 = fminf(12.0f,   gw) * fminf(28.75f,  gh);
    float i1 = fminf(9.875f,  gw) * fminf(23.25f,  gh);
    float i2 = fminf(10.125f, gw) * fminf(16.625f, gh);
    float iou0 = i0 / (345.0f      + 1e-16f + gwgh - i0);   // 12*28.75
    float iou1 = i1 / (229.59375f  + 1e-16f + gwgh - i1);   // 9.875*23.25
    float iou2 = i2 / (168.328125f + 1e-16f + gwgh - i2);   // 10.125*16.625
    int best = 0; float bv = iou0;
    if (iou1 > bv) { best = 1; bv = iou1; }
    if (iou2 > bv) { best = 2; bv = iou2; }
    float ioua = (a == 0) ? iou0 : ((a == 1) ? iou1 : iou2);
    bool at_t   = (ji == gj * NG + gi);
    bool isbest = (a == best);

    float tsum = 0.0f;
    // noobj BCE term (x100), skipped where reference zeroes the noobj mask
    if (!(at_t && (isbest || ioua > 0.5f)))
        tsum = -100.0f * fmaxf(__logf(1.0f - conf), -100.0f);
    // obj terms at the best-anchor target cell
    if (at_t && isbest) {
        tsum += -fmaxf(__logf(conf), -100.0f);            // conf BCE, t=1
        float txv = gx - (float)gi;
        float tyv = gy - (float)gj;
        float abw = (best == 0) ? 12.0f  : ((best == 1) ? 9.875f : 10.125f);
        float abh = (best == 0) ? 28.75f : ((best == 1) ? 23.25f : 16.625f);
        float twv = __logf(gw / abw + 1e-16f);
        float thv = __logf(gh / abh + 1e-16f);
        tsum += fabsf(v[0]*0.125f - txv) + fabsf(v[1]*0.125f - tyv)
              + fabsf(v[2]*0.125f - twv) + fabsf(v[3]*0.125f - thv);
        #pragma unroll
        for (int c = 0; c < NCLS; c++) {
            float p = v[5+c];
            tsum += (c == gcls) ? -fmaxf(__logf(p),        -100.0f)
                                : -fmaxf(__logf(1.0f - p), -100.0f);
        }
    }

    // shifted LDS layout for aligned float4 stores
    int base = t * NCH - 3;
    #pragma unroll
    for (int c = 0; c < NCH; c++) {
        int L = base + c;
        if (L < 0) L += FPB;                   // only t==0, c<3
        sm[L] = v[c];
    }

    // wave reduce loss partial
    #pragma unroll
    for (int off = 32; off > 0; off >>= 1) tsum += __shfl_down(tsum, off, 64);
    if ((t & 63) == 0) wred[t >> 6] = tsum;

    __syncthreads();

    // coalesced nontemporal float4 stores of the block's contiguous out region
    size_t gbase = (size_t)blockIdx.x * FPB;   // out[0] is loss; tensor starts at out+1
    f4* __restrict__ op = (f4*)(out + gbase + 4);
    const f4* __restrict__ sp = (const f4*)sm;
    #pragma unroll
    for (int k = 0; k < 5; k++) {
        int q = k * BLK + t;
        if (q < NQUAD) __builtin_nontemporal_store(sp[q], &op[q]);
    }

    if (t == 0) {
        out[gbase + 1]   = sm[FPB - 3];        // leading 3 floats
        out[gbase + 2]   = sm[FPB - 2];
        out[gbase + 3]   = sm[FPB - 1];
        out[gbase + FPB] = sm[FPB - 4];        // trailing scalar

        // deterministic cross-block reduce: exact integer fixed-point atomics.
        // per-block partial (float) is identical to the old two-kernel version;
        // only the cross-block accumulation changes (float tree -> exact int).
        float part = wred[0] + wred[1] + wred[2] + wred[3];
        long long fx = (long long)((double)part * FIXSCALE);
        atomicAdd(ws, (unsigned long long)fx);
        __threadfence();
        unsigned int* cnt = (unsigned int*)(ws + 1);
        unsigned int old = atomicAdd(cnt, 1u);
        if (old == NBLK - 1) {                 // last block finalizes the loss
            __threadfence();
            unsigned long long acc = atomicAdd(ws, 0ULL);   // coherent read
            double total = (double)(long long)acc * (1.0 / FIXSCALE);
            out[0] = (float)total;
        }
    }
}

extern "C" void kernel_launch(void* const* d_in, const int* in_sizes, int n_in,
                              void* d_out, int out_size, void* d_ws, size_t ws_size,
                              hipStream_t stream) {
    const float* x      = (const float*)d_in[0];
    const float* labels = (const float*)d_in[1];
    float* out = (float*)d_out;
    unsigned long long* ws = (unsigned long long*)d_ws;

    hipMemsetAsync(d_ws, 0, 16, stream);       // zero accumulator + counter
    hipLaunchKernelGGL(main_kernel, dim3(NBLK), dim3(BLK), 0, stream,
                       x, labels, out, ws);
}

// Round 4
// 212.104 us; speedup vs baseline: 1.6385x; 1.6385x over previous
//
#include <hip/hip_runtime.h>
#include <math.h>

#define NB    128
#define NG    52
#define NGG   2704          // NG*NG
#define NA    3
#define NCLS  15
#define NCH   20
#define NQ    8112          // NA*NGG
#define TOTAL 1038336       // NB*NQ
#define BLK   256
#define NBLK  (TOTAL/BLK)   // 4056 (exact)
#define FPB   (BLK*NCH)     // 5120 floats = 20.5 KB LDS
#define NQUAD ((FPB-4)/4)   // 1279 aligned float4 stores per block

typedef float f4 __attribute__((ext_vector_type(4)));

// ws layout: [0] u64 fixed-point loss accumulator, [1] u32 done-counter
#define FIXSCALE 4294967296.0   // 2^32

// ---- fused kernel: transform + all loss terms + fence-free deterministic reduce
__global__ __launch_bounds__(BLK) void main_kernel(const float* __restrict__ x,
                                                   const float* __restrict__ labels,
                                                   float* __restrict__ out,
                                                   unsigned long long* __restrict__ ws) {
    __shared__ __align__(16) float sm[FPB];   // block's 5120 out floats, shifted by -3
    __shared__ float wred[BLK/64];

    int t = threadIdx.x;
    int cell = blockIdx.x * BLK + t;          // one cell per thread
    int b  = cell / NQ;
    int r  = cell - b * NQ;
    int a  = r / NGG;
    int ji = r - a * NGG;

    const float* __restrict__ xp = x + ((size_t)(b*60 + a*20)) * NGG + ji;
    float z[NCH];
    #pragma unroll
    for (int c = 0; c < NCH; c++) z[c] = xp[c * NGG];

    float v[NCH];
    float conf = 1.0f / (1.0f + __expf(-z[4]));
    v[0] = 8.0f / (1.0f + __expf(-z[0]));
    v[1] = 8.0f / (1.0f + __expf(-z[1]));
    v[2] = 8.0f * z[2];
    v[3] = 8.0f * z[3];
    v[4] = conf;
    float m = z[5];
    #pragma unroll
    for (int c = 6; c < NCH; c++) m = fmaxf(m, z[c]);
    float s = 0.0f;
    #pragma unroll
    for (int c = 0; c < NCLS; c++) { v[5+c] = __expf(z[5+c] - m); s += v[5+c]; }
    float inv = 1.0f / s;
    #pragma unroll
    for (int c = 0; c < NCLS; c++) v[5+c] *= inv;

    // ---- per-batch target logic ----
    float gx = labels[b*5+0] * (float)NG;
    float gy = labels[b*5+1] * (float)NG;
    float gw = labels[b*5+2] * (float)NG;
    float gh = labels[b*5+3] * (float)NG;
    int  gcls = (int)labels[b*5+4];
    int gi = (int)gx, gj = (int)gy;
    float gwgh = gw * gh;
    float i0 = fminf(12.0f,   gw) * fminf(28.75f,  gh);
    float i1 = fminf(9.875f,  gw) * fminf(23.25f,  gh);
    float i2 = fminf(10.125f, gw) * fminf(16.625f, gh);
    float iou0 = i0 / (345.0f      + 1e-16f + gwgh - i0);   // 12*28.75
    float iou1 = i1 / (229.59375f  + 1e-16f + gwgh - i1);   // 9.875*23.25
    float iou2 = i2 / (168.328125f + 1e-16f + gwgh - i2);   // 10.125*16.625
    int best = 0; float bv = iou0;
    if (iou1 > bv) { best = 1; bv = iou1; }
    if (iou2 > bv) { best = 2; bv = iou2; }
    float ioua = (a == 0) ? iou0 : ((a == 1) ? iou1 : iou2);
    bool at_t   = (ji == gj * NG + gi);
    bool isbest = (a == best);

    float tsum = 0.0f;
    // noobj BCE term (x100), skipped where reference zeroes the noobj mask
    if (!(at_t && (isbest || ioua > 0.5f)))
        tsum = -100.0f * fmaxf(__logf(1.0f - conf), -100.0f);
    // obj terms at the best-anchor target cell
    if (at_t && isbest) {
        tsum += -fmaxf(__logf(conf), -100.0f);            // conf BCE, t=1
        float txv = gx - (float)gi;
        float tyv = gy - (float)gj;
        float abw = (best == 0) ? 12.0f  : ((best == 1) ? 9.875f : 10.125f);
        float abh = (best == 0) ? 28.75f : ((best == 1) ? 23.25f : 16.625f);
        float twv = __logf(gw / abw + 1e-16f);
        float thv = __logf(gh / abh + 1e-16f);
        tsum += fabsf(v[0]*0.125f - txv) + fabsf(v[1]*0.125f - tyv)
              + fabsf(v[2]*0.125f - twv) + fabsf(v[3]*0.125f - thv);
        #pragma unroll
        for (int c = 0; c < NCLS; c++) {
            float p = v[5+c];
            tsum += (c == gcls) ? -fmaxf(__logf(p),        -100.0f)
                                : -fmaxf(__logf(1.0f - p), -100.0f);
        }
    }

    // shifted LDS layout for aligned float4 stores
    int base = t * NCH - 3;
    #pragma unroll
    for (int c = 0; c < NCH; c++) {
        int L = base + c;
        if (L < 0) L += FPB;                   // only t==0, c<3
        sm[L] = v[c];
    }

    // wave reduce loss partial
    #pragma unroll
    for (int off = 32; off > 0; off >>= 1) tsum += __shfl_down(tsum, off, 64);
    if ((t & 63) == 0) wred[t >> 6] = tsum;

    __syncthreads();

    // coalesced nontemporal float4 stores of the block's contiguous out region
    size_t gbase = (size_t)blockIdx.x * FPB;   // out[0] is loss; tensor starts at out+1
    f4* __restrict__ op = (f4*)(out + gbase + 4);
    const f4* __restrict__ sp = (const f4*)sm;
    #pragma unroll
    for (int k = 0; k < 5; k++) {
        int q = k * BLK + t;
        if (q < NQUAD) __builtin_nontemporal_store(sp[q], &op[q]);
    }

    if (t == 0) {
        out[gbase + 1]   = sm[FPB - 3];        // leading 3 floats
        out[gbase + 2]   = sm[FPB - 2];
        out[gbase + 3]   = sm[FPB - 1];
        out[gbase + FPB] = sm[FPB - 4];        // trailing scalar

        // ---- fence-free deterministic cross-block reduce ----
        // Exact integer fixed-point accumulation (order-independent).
        // Atomic RMWs are device-coherent on gfx950 (execute at the coherence
        // point); NO __threadfence (R3 showed per-block device fences cost
        // ~190us via per-XCD L2 writebacks). Ordering acc-add -> cnt-add is
        // enforced by a data dependency on the first atomic's return value.
        float part = wred[0] + wred[1] + wred[2] + wred[3];
        long long fx = (long long)((double)part * FIXSCALE);
        unsigned long long old = atomicAdd(ws, (unsigned long long)fx);
        asm volatile("" : "+v"(old));                   // keep 'old' opaque
        unsigned int inc = 1u + (unsigned int)(old >> 63);  // always 1 (sum>0), real dep
        unsigned int* cnt = (unsigned int*)(ws + 1);
        unsigned int done = atomicAdd(cnt, inc);
        if (done == NBLK - 1) {                 // last block finalizes the loss
            asm volatile("" ::: "memory");
            unsigned long long acc = atomicAdd(ws, 0ULL);   // RMW read at coherence point
            double total = (double)(long long)acc * (1.0 / FIXSCALE);
            out[0] = (float)total;
        }
    }
}

extern "C" void kernel_launch(void* const* d_in, const int* in_sizes, int n_in,
                              void* d_out, int out_size, void* d_ws, size_t ws_size,
                              hipStream_t stream) {
    const float* x      = (const float*)d_in[0];
    const float* labels = (const float*)d_in[1];
    float* out = (float*)d_out;
    unsigned long long* ws = (unsigned long long*)d_ws;

    hipMemsetAsync(d_ws, 0, 16, stream);       // zero accumulator + counter
    hipLaunchKernelGGL(main_kernel, dim3(NBLK), dim3(BLK), 0, stream,
                       x, labels, out, ws);
}

// Round 5
// 154.268 us; speedup vs baseline: 2.2528x; 1.3749x over previous
//
#include <hip/hip_runtime.h>
#include <math.h>

#define NB    128
#define NG    52
#define NGG   2704          // NG*NG
#define NA    3
#define NCLS  15
#define NCH   20
#define NQ    8112          // NA*NGG
#define TOTAL 1038336       // NB*NQ
#define BLK   256
#define NBLK  (TOTAL/BLK)   // 4056 (exact)
#define WPB   (BLK/64)      // 4 waves per block
#define FPW   (64*NCH)      // 1280 floats staged per wave
#define NPART (NBLK*WPB)    // 16224 per-wave partials

typedef float f4 __attribute__((ext_vector_type(4)));

// ---- main kernel: transform + loss terms; wave-synchronous restage, NO barriers
__global__ __launch_bounds__(BLK) void main_kernel(const float* __restrict__ x,
                                                   const float* __restrict__ labels,
                                                   float* __restrict__ out,
                                                   float* __restrict__ partials) {
    __shared__ __align__(16) float sm[WPB][FPW];   // private row per wave

    int t = threadIdx.x;
    int w = t >> 6;                   // wave id in block
    int l = t & 63;                   // lane
    int cell = blockIdx.x * BLK + t;  // one cell per thread
    int b  = cell / NQ;
    int r  = cell - b * NQ;
    int a  = r / NGG;
    int ji = r - a * NGG;

    const float* __restrict__ xp = x + ((size_t)(b*60 + a*20)) * NGG + ji;
    float z[NCH];
    #pragma unroll
    for (int c = 0; c < NCH; c++) z[c] = xp[c * NGG];

    float v[NCH];
    float conf = 1.0f / (1.0f + __expf(-z[4]));
    v[0] = 8.0f / (1.0f + __expf(-z[0]));
    v[1] = 8.0f / (1.0f + __expf(-z[1]));
    v[2] = 8.0f * z[2];
    v[3] = 8.0f * z[3];
    v[4] = conf;
    float m = z[5];
    #pragma unroll
    for (int c = 6; c < NCH; c++) m = fmaxf(m, z[c]);
    float s = 0.0f;
    #pragma unroll
    for (int c = 0; c < NCLS; c++) { v[5+c] = __expf(z[5+c] - m); s += v[5+c]; }
    float inv = 1.0f / s;
    #pragma unroll
    for (int c = 0; c < NCLS; c++) v[5+c] *= inv;

    // ---- per-batch target logic ----
    float gx = labels[b*5+0] * (float)NG;
    float gy = labels[b*5+1] * (float)NG;
    float gw = labels[b*5+2] * (float)NG;
    float gh = labels[b*5+3] * (float)NG;
    int  gcls = (int)labels[b*5+4];
    int gi = (int)gx, gj = (int)gy;
    float gwgh = gw * gh;
    float i0 = fminf(12.0f,   gw) * fminf(28.75f,  gh);
    float i1 = fminf(9.875f,  gw) * fminf(23.25f,  gh);
    float i2 = fminf(10.125f, gw) * fminf(16.625f, gh);
    float iou0 = i0 / (345.0f      + 1e-16f + gwgh - i0);   // 12*28.75
    float iou1 = i1 / (229.59375f  + 1e-16f + gwgh - i1);   // 9.875*23.25
    float iou2 = i2 / (168.328125f + 1e-16f + gwgh - i2);   // 10.125*16.625
    int best = 0; float bv = iou0;
    if (iou1 > bv) { best = 1; bv = iou1; }
    if (iou2 > bv) { best = 2; bv = iou2; }
    float ioua = (a == 0) ? iou0 : ((a == 1) ? iou1 : iou2);
    bool at_t   = (ji == gj * NG + gi);
    bool isbest = (a == best);

    float tsum = 0.0f;
    // noobj BCE term (x100), skipped where reference zeroes the noobj mask
    if (!(at_t && (isbest || ioua > 0.5f)))
        tsum = -100.0f * fmaxf(__logf(1.0f - conf), -100.0f);
    // obj terms at the best-anchor target cell
    if (at_t && isbest) {
        tsum += -fmaxf(__logf(conf), -100.0f);            // conf BCE, t=1
        float txv = gx - (float)gi;
        float tyv = gy - (float)gj;
        float abw = (best == 0) ? 12.0f  : ((best == 1) ? 9.875f : 10.125f);
        float abh = (best == 0) ? 28.75f : ((best == 1) ? 23.25f : 16.625f);
        float twv = __logf(gw / abw + 1e-16f);
        float thv = __logf(gh / abh + 1e-16f);
        tsum += fabsf(v[0]*0.125f - txv) + fabsf(v[1]*0.125f - tyv)
              + fabsf(v[2]*0.125f - twv) + fabsf(v[3]*0.125f - thv);
        #pragma unroll
        for (int c = 0; c < NCLS; c++) {
            float p = v[5+c];
            tsum += (c == gcls) ? -fmaxf(__logf(p),        -100.0f)
                                : -fmaxf(__logf(1.0f - p), -100.0f);
        }
    }

    // per-wave shifted LDS restage (wrap only for lane 0, c<3)
    float* __restrict__ smw = sm[w];
    int base = l * NCH - 3;
    #pragma unroll
    for (int c = 0; c < NCH; c++) {
        int L = base + c;
        if (L < 0) L += FPW;
        smw[L] = v[c];
    }

    // wave reduce loss partial (lane 0 ends with the wave sum)
    #pragma unroll
    for (int off = 32; off > 0; off >>= 1) tsum += __shfl_down(tsum, off, 64);

    // wave-synchronous readback: lanes are lockstep; compiler orders ds ops
    // (lgkmcnt drain) -- NO __syncthreads anywhere in this kernel.
    int cell0 = blockIdx.x * BLK + w * 64;                 // wave's first cell
    size_t gf = 1 + (size_t)cell0 * NCH;                   // first out float of wave region
    f4* __restrict__ op = (f4*)(out + gf + 3);             // 16B-aligned (gf+3 = 4+cell0*20)
    const f4* __restrict__ sp = (const f4*)smw;
    #pragma unroll
    for (int k = 0; k < 5; k++) {
        int q = k * 64 + l;
        if (q < (FPW - 4) / 4) __builtin_nontemporal_store(sp[q], &op[q]);  // 319 f4
    }
    if (l == 0) {
        out[gf + 0]       = smw[FPW - 3];   // head 3 floats (wrapped)
        out[gf + 1]       = smw[FPW - 2];
        out[gf + 2]       = smw[FPW - 1];
        out[gf + FPW - 1] = smw[FPW - 4];   // tail scalar
        partials[blockIdx.x * WPB + w] = tsum;
    }
}

// ---- finish: deterministic reduction of 16224 per-wave partials ----
__global__ __launch_bounds__(1024) void finish_kernel(const float* __restrict__ partials,
                                                      float* __restrict__ out) {
    int t = threadIdx.x;   // 1024 threads
    float s = 0.0f;
    #pragma unroll
    for (int k = 0; k < NPART/1024 + 1; k++) {
        int q = k * 1024 + t;
        if (q < NPART) s += partials[q];
    }
    __shared__ float red[1024];
    red[t] = s;
    __syncthreads();
    for (int k = 512; k > 0; k >>= 1) {
        if (t < k) red[t] += red[t + k];
        __syncthreads();
    }
    if (t == 0) out[0] = red[0];
}

extern "C" void kernel_launch(void* const* d_in, const int* in_sizes, int n_in,
                              void* d_out, int out_size, void* d_ws, size_t ws_size,
                              hipStream_t stream) {
    const float* x      = (const float*)d_in[0];
    const float* labels = (const float*)d_in[1];
    float* out = (float*)d_out;
    float* ws  = (float*)d_ws;

    hipLaunchKernelGGL(main_kernel,   dim3(NBLK), dim3(BLK),  0, stream, x, labels, out, ws);
    hipLaunchKernelGGL(finish_kernel, dim3(1),    dim3(1024), 0, stream, ws, out);
}